// Round 2
// baseline (617.021 us; speedup 1.0000x reference)
//
#include <hip/hip_runtime.h>
#include <math.h>

#define K_COMP 64
#define D 32
#define NTRIL (D*(D-1)/2)          // 496
#define ICF_COLS (D + NTRIL)       // 528
#define BLK 256
#define PTS_PER_BLK 64
#define K_PER_WAVE 16

// compile-time (row, col) lookup for the column-major packed strict-lower-tri
struct TrilIdx { unsigned char r[NTRIL]; unsigned char c[NTRIL]; };
constexpr TrilIdx make_tril() {
  TrilIdx t{};
  int p = 0;
  for (int c = 0; c < D; ++c)
    for (int r = c + 1; r < D; ++r) { t.r[p] = (unsigned char)r; t.c[p] = (unsigned char)c; ++p; }
  return t;
}
constexpr TrilIdx TRIL = make_tril();

// ws layout (floats):
// [0,           2048) Qd[k][i]
// [2048,        4096) b[k][i] = M[k] @ means[k]
// [4096,        4160) ak[k] = alphas[k] + sum_qs[k]
// [4160,        4224) wk[k] = per-k wishart term
// [4224,        ... ) partials[nblocks]

__global__ __launch_bounds__(K_COMP) void gmm_prep(
    const float* __restrict__ alphas, const float* __restrict__ means,
    const float* __restrict__ icf, const float* __restrict__ wg,
    const float* __restrict__ wm, float* __restrict__ ws)
{
  int k = threadIdx.x;            // one thread per component
  const float* ick = icf + k * ICF_COLS;
  const float* mk  = means + k * D;

  float qd[D], b[D], mr[D];
  float sumq = 0.f, qsq = 0.f;
#pragma unroll
  for (int i = 0; i < D; ++i) {
    float v = ick[i];
    sumq += v;
    float q = __expf(v);
    qd[i] = q;
    qsq = fmaf(q, q, qsq);
  }
#pragma unroll
  for (int i = 0; i < D; ++i) { mr[i] = mk[i]; b[i] = qd[i] * mr[i]; }

  float lsq = 0.f;
#pragma unroll
  for (int p = 0; p < NTRIL; ++p) {
    float l = ick[D + p];
    b[TRIL.r[p]] = fmaf(l, mr[TRIL.c[p]], b[TRIL.r[p]]);
    lsq = fmaf(l, l, lsq);
  }

  float* wqd = ws;
  float* wb  = ws + K_COMP * D;
  float* wak = ws + 2 * K_COMP * D;
  float* wwk = wak + K_COMP;
#pragma unroll
  for (int i = 0; i < D; ++i) { wqd[k*D + i] = qd[i]; wb[k*D + i] = b[i]; }
  wak[k] = alphas[k] + sumq;
  float g = wg[0], m = wm[0];
  wwk[k] = 0.5f * g * g * (qsq + lsq) - m * sumq;
}

__global__ __launch_bounds__(BLK, 4) void gmm_main(
    const float* __restrict__ x, const float* __restrict__ icf,
    const float* __restrict__ ws, int N, float* __restrict__ partials)
{
  const float* wqd = ws;
  const float* wb  = ws + K_COMP * D;
  const float* wak = ws + 2 * K_COMP * D;

  int tid  = threadIdx.x;
  int lane = tid & 63;
  int wv   = __builtin_amdgcn_readfirstlane(tid >> 6);  // wave-uniform
  int n = blockIdx.x * PTS_PER_BLK + lane;
  bool valid = n < N;
  int nn = valid ? n : (N - 1);

  float xr[D];
  const float4* xp = reinterpret_cast<const float4*>(x + (size_t)nn * D);
#pragma unroll
  for (int i = 0; i < D / 4; ++i) {
    float4 v = xp[i];
    xr[4*i+0] = v.x; xr[4*i+1] = v.y; xr[4*i+2] = v.z; xr[4*i+3] = v.w;
  }

  float m = -INFINITY, s = 0.f;
  int k0 = wv * K_PER_WAVE;
#pragma unroll 1
  for (int k = k0; k < k0 + K_PER_WAVE; ++k) {
    const float* qk = wqd + k * D;            // uniform -> s_load
    const float* bk = wb  + k * D;            // uniform -> s_load
    const float* lk = icf + k * ICF_COLS + D; // uniform -> s_load

    float lx[D];
#pragma unroll
    for (int i = 0; i < D; ++i) lx[i] = fmaf(qk[i], xr[i], -bk[i]);

    // flat constant-trip loop: full unroll -> static indices -> registers
#pragma unroll
    for (int p = 0; p < NTRIL; ++p)
      lx[TRIL.r[p]] = fmaf(lk[p], xr[TRIL.c[p]], lx[TRIL.r[p]]);

    float s0 = 0.f, s1 = 0.f, s2 = 0.f, s3 = 0.f;
#pragma unroll
    for (int i = 0; i < D; i += 4) {
      s0 = fmaf(lx[i+0], lx[i+0], s0);
      s1 = fmaf(lx[i+1], lx[i+1], s1);
      s2 = fmaf(lx[i+2], lx[i+2], s2);
      s3 = fmaf(lx[i+3], lx[i+3], s3);
    }
    float sq = (s0 + s1) + (s2 + s3);
    float inner = wak[k] - 0.5f * sq;

    // branchless online logsumexp over this wave's k-slice
    float mn = fmaxf(m, inner);
    s = s * __expf(m - mn) + __expf(inner - mn);
    m = mn;
  }

  // merge the 4 per-wave (m,s) partials for each point via LDS
  __shared__ float lm[4][PTS_PER_BLK];
  __shared__ float ls[4][PTS_PER_BLK];
  lm[wv][lane] = m;
  ls[wv][lane] = s;
  __syncthreads();

  if (tid < PTS_PER_BLK) {
    float mm = lm[0][tid];
#pragma unroll
    for (int w = 1; w < 4; ++w) mm = fmaxf(mm, lm[w][tid]);
    float ss = 0.f;
#pragma unroll
    for (int w = 0; w < 4; ++w) ss += ls[w][tid] * __expf(lm[w][tid] - mm);
    float lse = valid ? (mm + __logf(ss)) : 0.f;
#pragma unroll
    for (int off = 32; off > 0; off >>= 1) lse += __shfl_down(lse, off);
    if (tid == 0) partials[blockIdx.x] = lse;
  }
}

__global__ __launch_bounds__(256) void gmm_final(
    const float* __restrict__ ws, int nblocks,
    const float* __restrict__ alphas, const float* __restrict__ wg,
    const float* __restrict__ wm, int N, float* __restrict__ out)
{
  const float* wwk = ws + 2 * K_COMP * D + K_COMP;
  const float* partials = wwk + K_COMP;

  int tid = threadIdx.x;
  __shared__ double sacc[256];
  double acc = 0.0;
  for (int i = tid; i < nblocks; i += 256) acc += (double)partials[i];
  sacc[tid] = acc;
  __syncthreads();
  for (int st = 128; st > 0; st >>= 1) {
    if (tid < st) sacc[tid] += sacc[tid + st];
    __syncthreads();
  }

  if (tid == 0) {
    double slse = sacc[0];

    float amax = alphas[0];
    for (int k = 1; k < K_COMP; ++k) amax = fmaxf(amax, alphas[k]);
    double sa = 0.0;
    for (int k = 0; k < K_COMP; ++k) sa += exp((double)(alphas[k] - amax));
    double lse_a = (double)amax + log(sa);

    double ow = 0.0;
    for (int k = 0; k < K_COMP; ++k) ow += (double)wwk[k];

    double g = (double)wg[0], wmv = (double)wm[0];
    double nw = (double)D + wmv + 1.0;
    double C = nw * (double)D * log(g / sqrt(2.0));
    double mg = (D * (D - 1) / 4.0) * log(M_PI);
    for (int j = 1; j <= D; ++j) mg += lgamma(0.5 * nw + (1.0 - j) * 0.5);

    double CONST = -(double)N * D * 0.5 * log(2.0 * M_PI);
    double prior = ow - (double)K_COMP * (C - mg);

    out[0] = (float)(CONST + slse - (double)N * lse_a + prior);
  }
}

extern "C" void kernel_launch(void* const* d_in, const int* in_sizes, int n_in,
                              void* d_out, int out_size, void* d_ws, size_t ws_size,
                              hipStream_t stream)
{
  const float* alphas = (const float*)d_in[0];
  const float* means  = (const float*)d_in[1];
  const float* icf    = (const float*)d_in[2];
  const float* x      = (const float*)d_in[3];
  const float* wg     = (const float*)d_in[4];
  const float* wm     = (const float*)d_in[5];
  float* out = (float*)d_out;
  float* ws  = (float*)d_ws;

  int N = in_sizes[3] / D;
  int nblocks = (N + PTS_PER_BLK - 1) / PTS_PER_BLK;
  float* partials = ws + 2 * K_COMP * D + 2 * K_COMP;

  gmm_prep<<<1, K_COMP, 0, stream>>>(alphas, means, icf, wg, wm, ws);
  gmm_main<<<nblocks, BLK, 0, stream>>>(x, icf, ws, N, partials);
  gmm_final<<<1, 256, 0, stream>>>(ws, nblocks, alphas, wg, wm, N, out);
}

// Round 3
// 247.133 us; speedup vs baseline: 2.4967x; 2.4967x over previous
//
#include <hip/hip_runtime.h>
#include <math.h>
#include <utility>

#define K_COMP 64
#define D 32
#define NTRIL (D*(D-1)/2)          // 496
#define ICF_COLS (D + NTRIL)       // 528
#define BLK 256
#define PTS_PER_BLK 64
#define K_PER_WAVE 16

// compile-time (row, col) from packed column-major strict-lower-tri index
constexpr int tril_c_of(int p) {
  int c = 0, off = 0;
  while (off + (D - 1 - c) <= p) { off += D - 1 - c; ++c; }
  return c;
}
constexpr int tril_off_of_col(int c) {
  int off = 0;
  for (int j = 0; j < c; ++j) off += D - 1 - j;
  return off;
}
constexpr int tril_r_of(int p) {
  int c = tril_c_of(p);
  return c + 1 + (p - tril_off_of_col(c));
}

// one FMA of the triangular matvec; indices forced compile-time via constexpr
template<int P>
__device__ __forceinline__ void tril_step(const float* __restrict__ lk,
                                          const float (&xr)[D], float (&lx)[D]) {
  constexpr int r = tril_r_of(P);
  constexpr int c = tril_c_of(P);
  lx[r] = fmaf(lk[P], xr[c], lx[r]);
}
template<size_t... Ps>
__device__ __forceinline__ void tril_matvec(const float* __restrict__ lk,
                                            const float (&xr)[D], float (&lx)[D],
                                            std::index_sequence<Ps...>) {
  (tril_step<(int)Ps>(lk, xr, lx), ...);
}

// prep variant: also accumulates sum of squares of L entries
template<int P>
__device__ __forceinline__ void tril_step_prep(const float* __restrict__ lk,
                                               const float (&mr)[D], float (&b)[D],
                                               float& lsq) {
  constexpr int r = tril_r_of(P);
  constexpr int c = tril_c_of(P);
  float l = lk[P];
  b[r] = fmaf(l, mr[c], b[r]);
  lsq = fmaf(l, l, lsq);
}
template<size_t... Ps>
__device__ __forceinline__ void tril_matvec_prep(const float* __restrict__ lk,
                                                 const float (&mr)[D], float (&b)[D],
                                                 float& lsq,
                                                 std::index_sequence<Ps...>) {
  (tril_step_prep<(int)Ps>(lk, mr, b, lsq), ...);
}

// ws layout (floats):
// [0,           2048) Qd[k][i]
// [2048,        4096) b[k][i] = M[k] @ means[k]
// [4096,        4160) ak[k] = alphas[k] + sum_qs[k]
// [4160,        4224) wk[k] = per-k wishart term
// [4224,        ... ) partials[nblocks]

__global__ __launch_bounds__(K_COMP) void gmm_prep(
    const float* __restrict__ alphas, const float* __restrict__ means,
    const float* __restrict__ icf, const float* __restrict__ wg,
    const float* __restrict__ wm, float* __restrict__ ws)
{
  int k = threadIdx.x;            // one thread per component
  const float* ick = icf + k * ICF_COLS;
  const float* mk  = means + k * D;

  float qd[D], b[D], mr[D];
  float sumq = 0.f, qsq = 0.f;
#pragma unroll
  for (int i = 0; i < D; ++i) {
    float v = ick[i];
    sumq += v;
    float q = __expf(v);
    qd[i] = q;
    qsq = fmaf(q, q, qsq);
  }
#pragma unroll
  for (int i = 0; i < D; ++i) { mr[i] = mk[i]; b[i] = qd[i] * mr[i]; }

  float lsq = 0.f;
  tril_matvec_prep(ick + D, mr, b, lsq, std::make_index_sequence<NTRIL>{});

  float* wqd = ws;
  float* wb  = ws + K_COMP * D;
  float* wak = ws + 2 * K_COMP * D;
  float* wwk = wak + K_COMP;
#pragma unroll
  for (int i = 0; i < D; ++i) { wqd[k*D + i] = qd[i]; wb[k*D + i] = b[i]; }
  wak[k] = alphas[k] + sumq;
  float g = wg[0], m = wm[0];
  wwk[k] = 0.5f * g * g * (qsq + lsq) - m * sumq;
}

__global__ __launch_bounds__(BLK, 2) void gmm_main(
    const float* __restrict__ x, const float* __restrict__ icf,
    const float* __restrict__ ws, int N, float* __restrict__ partials)
{
  const float* wqd = ws;
  const float* wb  = ws + K_COMP * D;
  const float* wak = ws + 2 * K_COMP * D;

  int tid  = threadIdx.x;
  int lane = tid & 63;
  int wv   = __builtin_amdgcn_readfirstlane(tid >> 6);  // wave-uniform
  int n = blockIdx.x * PTS_PER_BLK + lane;
  bool valid = n < N;
  int nn = valid ? n : (N - 1);

  float xr[D];
  const float4* xp = reinterpret_cast<const float4*>(x + (size_t)nn * D);
#pragma unroll
  for (int i = 0; i < D / 4; ++i) {
    float4 v = xp[i];
    xr[4*i+0] = v.x; xr[4*i+1] = v.y; xr[4*i+2] = v.z; xr[4*i+3] = v.w;
  }

  float m = -INFINITY, s = 0.f;
  int k0 = wv * K_PER_WAVE;
#pragma unroll 1
  for (int k = k0; k < k0 + K_PER_WAVE; ++k) {
    const float* qk = wqd + k * D;            // uniform -> s_load
    const float* bk = wb  + k * D;            // uniform -> s_load
    const float* lk = icf + k * ICF_COLS + D; // uniform -> s_load

    float lx[D];
#pragma unroll
    for (int i = 0; i < D; ++i) lx[i] = fmaf(qk[i], xr[i], -bk[i]);

    // 496 straight-line FMAs, indices fixed at template-instantiation time
    tril_matvec(lk, xr, lx, std::make_index_sequence<NTRIL>{});

    float s0 = 0.f, s1 = 0.f, s2 = 0.f, s3 = 0.f;
#pragma unroll
    for (int i = 0; i < D; i += 4) {
      s0 = fmaf(lx[i+0], lx[i+0], s0);
      s1 = fmaf(lx[i+1], lx[i+1], s1);
      s2 = fmaf(lx[i+2], lx[i+2], s2);
      s3 = fmaf(lx[i+3], lx[i+3], s3);
    }
    float sq = (s0 + s1) + (s2 + s3);
    float inner = wak[k] - 0.5f * sq;

    // branchless online logsumexp over this wave's k-slice
    float mn = fmaxf(m, inner);
    s = s * __expf(m - mn) + __expf(inner - mn);
    m = mn;
  }

  // merge the 4 per-wave (m,s) partials for each point via LDS
  __shared__ float lm[4][PTS_PER_BLK];
  __shared__ float ls[4][PTS_PER_BLK];
  lm[wv][lane] = m;
  ls[wv][lane] = s;
  __syncthreads();

  if (tid < PTS_PER_BLK) {
    float mm = lm[0][tid];
#pragma unroll
    for (int w = 1; w < 4; ++w) mm = fmaxf(mm, lm[w][tid]);
    float ss = 0.f;
#pragma unroll
    for (int w = 0; w < 4; ++w) ss += ls[w][tid] * __expf(lm[w][tid] - mm);
    float lse = valid ? (mm + __logf(ss)) : 0.f;
#pragma unroll
    for (int off = 32; off > 0; off >>= 1) lse += __shfl_down(lse, off);
    if (tid == 0) partials[blockIdx.x] = lse;
  }
}

__global__ __launch_bounds__(256) void gmm_final(
    const float* __restrict__ ws, int nblocks,
    const float* __restrict__ alphas, const float* __restrict__ wg,
    const float* __restrict__ wm, int N, float* __restrict__ out)
{
  const float* wwk = ws + 2 * K_COMP * D + K_COMP;
  const float* partials = wwk + K_COMP;

  int tid = threadIdx.x;
  __shared__ double sacc[256];
  double acc = 0.0;
  for (int i = tid; i < nblocks; i += 256) acc += (double)partials[i];
  sacc[tid] = acc;
  __syncthreads();
  for (int st = 128; st > 0; st >>= 1) {
    if (tid < st) sacc[tid] += sacc[tid + st];
    __syncthreads();
  }

  if (tid == 0) {
    double slse = sacc[0];

    float amax = alphas[0];
    for (int k = 1; k < K_COMP; ++k) amax = fmaxf(amax, alphas[k]);
    double sa = 0.0;
    for (int k = 0; k < K_COMP; ++k) sa += exp((double)(alphas[k] - amax));
    double lse_a = (double)amax + log(sa);

    double ow = 0.0;
    for (int k = 0; k < K_COMP; ++k) ow += (double)wwk[k];

    double g = (double)wg[0], wmv = (double)wm[0];
    double nw = (double)D + wmv + 1.0;
    double C = nw * (double)D * log(g / sqrt(2.0));
    double mg = (D * (D - 1) / 4.0) * log(M_PI);
    for (int j = 1; j <= D; ++j) mg += lgamma(0.5 * nw + (1.0 - j) * 0.5);

    double CONST = -(double)N * D * 0.5 * log(2.0 * M_PI);
    double prior = ow - (double)K_COMP * (C - mg);

    out[0] = (float)(CONST + slse - (double)N * lse_a + prior);
  }
}

extern "C" void kernel_launch(void* const* d_in, const int* in_sizes, int n_in,
                              void* d_out, int out_size, void* d_ws, size_t ws_size,
                              hipStream_t stream)
{
  const float* alphas = (const float*)d_in[0];
  const float* means  = (const float*)d_in[1];
  const float* icf    = (const float*)d_in[2];
  const float* x      = (const float*)d_in[3];
  const float* wg     = (const float*)d_in[4];
  const float* wm     = (const float*)d_in[5];
  float* out = (float*)d_out;
  float* ws  = (float*)d_ws;

  int N = in_sizes[3] / D;
  int nblocks = (N + PTS_PER_BLK - 1) / PTS_PER_BLK;
  float* partials = ws + 2 * K_COMP * D + 2 * K_COMP;

  gmm_prep<<<1, K_COMP, 0, stream>>>(alphas, means, icf, wg, wm, ws);
  gmm_main<<<nblocks, BLK, 0, stream>>>(x, icf, ws, N, partials);
  gmm_final<<<1, 256, 0, stream>>>(ws, nblocks, alphas, wg, wm, N, out);
}

// Round 4
// 204.607 us; speedup vs baseline: 3.0156x; 1.2078x over previous
//
#include <hip/hip_runtime.h>
#include <math.h>
#include <utility>

#define K_COMP 64
#define D 32
#define NTRIL (D*(D-1)/2)          // 496
#define ICF_COLS (D + NTRIL)       // 528
#define BLK 256
#define PTS_PER_BLK 64
#define KSPLIT 4                   // k-blocks per point-block
#define K_PER_WAVE 4               // 4 waves * 4 k = 16 k per block

// compile-time (row, col) from packed column-major strict-lower-tri index
constexpr int tril_c_of(int p) {
  int c = 0, off = 0;
  while (off + (D - 1 - c) <= p) { off += D - 1 - c; ++c; }
  return c;
}
constexpr int tril_off_of_col(int c) {
  int off = 0;
  for (int j = 0; j < c; ++j) off += D - 1 - j;
  return off;
}
constexpr int tril_r_of(int p) {
  int c = tril_c_of(p);
  return c + 1 + (p - tril_off_of_col(c));
}

template<int P>
__device__ __forceinline__ void tril_step(const float* __restrict__ lk,
                                          const float (&xr)[D], float (&lx)[D]) {
  constexpr int r = tril_r_of(P);
  constexpr int c = tril_c_of(P);
  lx[r] = fmaf(lk[P], xr[c], lx[r]);
}
template<size_t... Ps>
__device__ __forceinline__ void tril_matvec(const float* __restrict__ lk,
                                            const float (&xr)[D], float (&lx)[D],
                                            std::index_sequence<Ps...>) {
  (tril_step<(int)Ps>(lk, xr, lx), ...);
}

template<int P>
__device__ __forceinline__ void tril_step_prep(const float* __restrict__ lk,
                                               const float (&mr)[D], float (&b)[D],
                                               float& lsq) {
  constexpr int r = tril_r_of(P);
  constexpr int c = tril_c_of(P);
  float l = lk[P];
  b[r] = fmaf(l, mr[c], b[r]);
  lsq = fmaf(l, l, lsq);
}
template<size_t... Ps>
__device__ __forceinline__ void tril_matvec_prep(const float* __restrict__ lk,
                                                 const float (&mr)[D], float (&b)[D],
                                                 float& lsq,
                                                 std::index_sequence<Ps...>) {
  (tril_step_prep<(int)Ps>(lk, mr, b, lsq), ...);
}

// ws layout (floats):
// [0,    2048) Qd[k][i]
// [2048, 4096) b[k][i] = M[k] @ means[k]
// [4096, 4160) ak[k] = alphas[k] + sum_qs[k]
// [4160, 4224) wk[k] = per-k wishart term
// [4224, 4224 + 2*KSPLIT*Npad)  ms[kb][n] = float2(m, s) per-point partials
// then   merge partials[nmerge]

__global__ __launch_bounds__(K_COMP) void gmm_prep(
    const float* __restrict__ alphas, const float* __restrict__ means,
    const float* __restrict__ icf, const float* __restrict__ wg,
    const float* __restrict__ wm, float* __restrict__ ws)
{
  int k = threadIdx.x;
  const float* ick = icf + k * ICF_COLS;
  const float* mk  = means + k * D;

  float qd[D], b[D], mr[D];
  float sumq = 0.f, qsq = 0.f;
#pragma unroll
  for (int i = 0; i < D; ++i) {
    float v = ick[i];
    sumq += v;
    float q = __expf(v);
    qd[i] = q;
    qsq = fmaf(q, q, qsq);
  }
#pragma unroll
  for (int i = 0; i < D; ++i) { mr[i] = mk[i]; b[i] = qd[i] * mr[i]; }

  float lsq = 0.f;
  tril_matvec_prep(ick + D, mr, b, lsq, std::make_index_sequence<NTRIL>{});

  float* wqd = ws;
  float* wb  = ws + K_COMP * D;
  float* wak = ws + 2 * K_COMP * D;
  float* wwk = wak + K_COMP;
#pragma unroll
  for (int i = 0; i < D; ++i) { wqd[k*D + i] = qd[i]; wb[k*D + i] = b[i]; }
  wak[k] = alphas[k] + sumq;
  float g = wg[0], m = wm[0];
  wwk[k] = 0.5f * g * g * (qsq + lsq) - m * sumq;
}

__global__ __launch_bounds__(BLK, 2) void gmm_main(
    const float* __restrict__ x, const float* __restrict__ icf,
    const float* __restrict__ ws, int N, int Npad, float2* __restrict__ ms)
{
  const float* wqd = ws;
  const float* wb  = ws + K_COMP * D;
  const float* wak = ws + 2 * K_COMP * D;

  int tid  = threadIdx.x;
  int lane = tid & 63;
  int wv   = __builtin_amdgcn_readfirstlane(tid >> 6);  // wave-uniform
  int kb   = blockIdx.x & (KSPLIT - 1);
  int pblk = blockIdx.x >> 2;
  int n = pblk * PTS_PER_BLK + lane;
  int nn = (n < N) ? n : (N - 1);

  float xr[D];
  const float4* xp = reinterpret_cast<const float4*>(x + (size_t)nn * D);
#pragma unroll
  for (int i = 0; i < D / 4; ++i) {
    float4 v = xp[i];
    xr[4*i+0] = v.x; xr[4*i+1] = v.y; xr[4*i+2] = v.z; xr[4*i+3] = v.w;
  }

  float m = -INFINITY, s = 0.f;
  int k0 = kb * (KSPLIT * K_PER_WAVE) + wv * K_PER_WAVE;
#pragma unroll 1
  for (int k = k0; k < k0 + K_PER_WAVE; ++k) {
    const float* qk = wqd + k * D;            // uniform -> s_load
    const float* bk = wb  + k * D;            // uniform -> s_load
    const float* lk = icf + k * ICF_COLS + D; // uniform -> s_load

    float lx[D];
#pragma unroll
    for (int i = 0; i < D; ++i) lx[i] = fmaf(qk[i], xr[i], -bk[i]);

    tril_matvec(lk, xr, lx, std::make_index_sequence<NTRIL>{});

    float s0 = 0.f, s1 = 0.f, s2 = 0.f, s3 = 0.f;
#pragma unroll
    for (int i = 0; i < D; i += 4) {
      s0 = fmaf(lx[i+0], lx[i+0], s0);
      s1 = fmaf(lx[i+1], lx[i+1], s1);
      s2 = fmaf(lx[i+2], lx[i+2], s2);
      s3 = fmaf(lx[i+3], lx[i+3], s3);
    }
    float sq = (s0 + s1) + (s2 + s3);
    float inner = wak[k] - 0.5f * sq;

    float mn = fmaxf(m, inner);
    s = s * __expf(m - mn) + __expf(inner - mn);
    m = mn;
  }

  // merge the 4 per-wave (m,s) partials for each point via LDS
  __shared__ float lm[4][PTS_PER_BLK];
  __shared__ float ls[4][PTS_PER_BLK];
  lm[wv][lane] = m;
  ls[wv][lane] = s;
  __syncthreads();

  if (tid < PTS_PER_BLK) {
    float mm = lm[0][tid];
#pragma unroll
    for (int w = 1; w < 4; ++w) mm = fmaxf(mm, lm[w][tid]);
    float ss = 0.f;
#pragma unroll
    for (int w = 0; w < 4; ++w) ss += ls[w][tid] * __expf(lm[w][tid] - mm);
    ms[(size_t)kb * Npad + pblk * PTS_PER_BLK + tid] = make_float2(mm, ss);
  }
}

__global__ __launch_bounds__(256) void gmm_merge(
    const float2* __restrict__ ms, int N, int Npad, float* __restrict__ partials)
{
  int tid = threadIdx.x;
  int idx = blockIdx.x * 256 + tid;
  int ii = (idx < N) ? idx : 0;

  float m[KSPLIT], s[KSPLIT];
#pragma unroll
  for (int kb = 0; kb < KSPLIT; ++kb) {
    float2 v = ms[(size_t)kb * Npad + ii];
    m[kb] = v.x; s[kb] = v.y;
  }
  float mm = m[0];
#pragma unroll
  for (int kb = 1; kb < KSPLIT; ++kb) mm = fmaxf(mm, m[kb]);
  float ss = 0.f;
#pragma unroll
  for (int kb = 0; kb < KSPLIT; ++kb) ss += s[kb] * __expf(m[kb] - mm);
  float lse = (idx < N) ? (mm + __logf(ss)) : 0.f;

  // block reduction
  __shared__ float red[256];
  red[tid] = lse;
  __syncthreads();
#pragma unroll
  for (int st = 128; st > 0; st >>= 1) {
    if (tid < st) red[tid] += red[tid + st];
    __syncthreads();
  }
  if (tid == 0) partials[blockIdx.x] = red[0];
}

__global__ __launch_bounds__(256) void gmm_final(
    const float* __restrict__ wwk, const float* __restrict__ partials, int nblocks,
    const float* __restrict__ alphas, const float* __restrict__ wg,
    const float* __restrict__ wm, int N, float* __restrict__ out)
{
  int tid = threadIdx.x;
  __shared__ double sacc[256];
  double acc = 0.0;
  for (int i = tid; i < nblocks; i += 256) acc += (double)partials[i];
  sacc[tid] = acc;
  __syncthreads();
  for (int st = 128; st > 0; st >>= 1) {
    if (tid < st) sacc[tid] += sacc[tid + st];
    __syncthreads();
  }

  if (tid == 0) {
    double slse = sacc[0];

    float amax = alphas[0];
    for (int k = 1; k < K_COMP; ++k) amax = fmaxf(amax, alphas[k]);
    double sa = 0.0;
    for (int k = 0; k < K_COMP; ++k) sa += exp((double)(alphas[k] - amax));
    double lse_a = (double)amax + log(sa);

    double ow = 0.0;
    for (int k = 0; k < K_COMP; ++k) ow += (double)wwk[k];

    double g = (double)wg[0], wmv = (double)wm[0];
    double nw = (double)D + wmv + 1.0;
    double C = nw * (double)D * log(g / sqrt(2.0));
    double mg = (D * (D - 1) / 4.0) * log(M_PI);
    for (int j = 1; j <= D; ++j) mg += lgamma(0.5 * nw + (1.0 - j) * 0.5);

    double CONST = -(double)N * D * 0.5 * log(2.0 * M_PI);
    double prior = ow - (double)K_COMP * (C - mg);

    out[0] = (float)(CONST + slse - (double)N * lse_a + prior);
  }
}

extern "C" void kernel_launch(void* const* d_in, const int* in_sizes, int n_in,
                              void* d_out, int out_size, void* d_ws, size_t ws_size,
                              hipStream_t stream)
{
  const float* alphas = (const float*)d_in[0];
  const float* means  = (const float*)d_in[1];
  const float* icf    = (const float*)d_in[2];
  const float* x      = (const float*)d_in[3];
  const float* wg     = (const float*)d_in[4];
  const float* wm     = (const float*)d_in[5];
  float* out = (float*)d_out;
  float* ws  = (float*)d_ws;

  int N = in_sizes[3] / D;
  int npblk = (N + PTS_PER_BLK - 1) / PTS_PER_BLK;   // 782
  int Npad  = npblk * PTS_PER_BLK;                    // 50048
  int nmerge = (N + 255) / 256;                       // 196

  float*  wwk      = ws + 2 * K_COMP * D + K_COMP;
  float2* ms       = (float2*)(ws + 2 * K_COMP * D + 2 * K_COMP);
  float*  partials = (float*)(ms + (size_t)KSPLIT * Npad);

  gmm_prep<<<1, K_COMP, 0, stream>>>(alphas, means, icf, wg, wm, ws);
  gmm_main<<<npblk * KSPLIT, BLK, 0, stream>>>(x, icf, ws, N, Npad, ms);
  gmm_merge<<<nmerge, 256, 0, stream>>>(ms, N, Npad, partials);
  gmm_final<<<1, 256, 0, stream>>>(wwk, partials, nmerge, alphas, wg, wm, N, out);
}